// Round 2
// baseline (498.233 us; speedup 1.0000x reference)
//
#include <hip/hip_runtime.h>
#include <hip/hip_bf16.h>
#include <stdint.h>

typedef __attribute__((ext_vector_type(8))) short short8;
typedef __attribute__((ext_vector_type(4))) float floatx4;

#define NB 4
#define NN 8192
#define NC 768
#define NH 12
#define ND 64
#define LDQKV 2304

// ---------- helpers ----------
__device__ __forceinline__ float bf2f(ushort u) {
    union { float f; uint32_t i; } x; x.i = ((uint32_t)u) << 16; return x.f;
}
__device__ __forceinline__ ushort f2bf(float f) {
    union { float f; uint32_t i; } x; x.f = f;
    uint32_t r = x.i + 0x7fff + ((x.i >> 16) & 1);
    return (ushort)(r >> 16);
}
// async global->LDS, 16B per lane: lane i lands at ldsbase + 16*i (wave-uniform base).
typedef const __attribute__((address_space(1))) uint32_t* gas1_t;
typedef __attribute__((address_space(3))) uint32_t* las3_t;
__device__ __forceinline__ void gl_lds16(const void* g, const void* l) {
    __builtin_amdgcn_global_load_lds((gas1_t)(uintptr_t)g,
                                     (las3_t)(uint32_t)(uintptr_t)l, 16, 0, 0);
}

// ---------- fp32 -> bf16 bulk convert (8 elems/thread, 16B stores) ----------
__global__ __launch_bounds__(256) void cvt_bf16(const float* __restrict__ src,
                                                ushort* __restrict__ dst, int n) {
    const int i = (blockIdx.x * 256 + threadIdx.x) * 8;
    if (i >= n) return;
    const float4 a = *(const float4*)(src + i);
    const float4 b = *(const float4*)(src + i + 4);
    short8 v;
    v[0] = (short)f2bf(a.x); v[1] = (short)f2bf(a.y);
    v[2] = (short)f2bf(a.z); v[3] = (short)f2bf(a.w);
    v[4] = (short)f2bf(b.x); v[5] = (short)f2bf(b.y);
    v[6] = (short)f2bf(b.z); v[7] = (short)f2bf(b.w);
    *(short8*)(dst + i) = v;
}

// ---------- GEMM: C[M, n-slice] = act(A[M,K] @ Bw[N,K]^T (+ bias)) ----------
// 128x128 block tile, 256 threads (4 waves, 2x2), 4x4 16x16x32 MFMA per wave.
// OutT: ushort (bf16 store) or float (fp32 store). bias (fp32) applied iff BIAS.
template<int LDC, bool ELU, bool BIAS, typename OutT>
__global__ __launch_bounds__(256) void gemm_bt(const ushort* __restrict__ A,
                                               const ushort* __restrict__ Bw,
                                               const float* __restrict__ bias,
                                               OutT* __restrict__ Cout, int K) {
    __shared__ ushort As[128 * 32];
    __shared__ ushort Bs[128 * 32];
    const int t = threadIdx.x;
    const int w = t >> 6, lane = t & 63, l16 = lane & 15, quad = lane >> 4;
    const int wm = w & 1, wn = w >> 1;
    const int m0 = blockIdx.y * 128, n0 = blockIdx.x * 128;

    floatx4 acc[4][4] = {};

    const int rowA = t >> 2, chA = t & 3;            // 64 rows x 4 chunks of 16B
    const ushort* gA = A  + (size_t)(m0 + rowA) * K + chA * 8;
    const ushort* gB = Bw + (size_t)(n0 + rowA) * K + chA * 8;

    for (int k0 = 0; k0 < K; k0 += 32) {
        gl_lds16(gA + k0,                As + w * 512);
        gl_lds16(gA + k0 + 64 * K,       As + 2048 + w * 512);
        gl_lds16(gB + k0,                Bs + w * 512);
        gl_lds16(gB + k0 + 64 * K,       Bs + 2048 + w * 512);
        __syncthreads();
        short8 af[4], bfr[4];
        #pragma unroll
        for (int i = 0; i < 4; i++)
            af[i] = *(const short8*)&As[(wm * 64 + i * 16 + l16) * 32 + quad * 8];
        #pragma unroll
        for (int j = 0; j < 4; j++)
            bfr[j] = *(const short8*)&Bs[(wn * 64 + j * 16 + l16) * 32 + quad * 8];
        #pragma unroll
        for (int i = 0; i < 4; i++)
            #pragma unroll
            for (int j = 0; j < 4; j++)
                acc[i][j] = __builtin_amdgcn_mfma_f32_16x16x32_bf16(af[i], bfr[j], acc[i][j], 0, 0, 0);
        __syncthreads();
    }

    #pragma unroll
    for (int i = 0; i < 4; i++) {
        const int row = m0 + wm * 64 + i * 16 + quad * 4;
        #pragma unroll
        for (int j = 0; j < 4; j++) {
            const int col = n0 + wn * 64 + j * 16 + l16;
            float bval = 0.f;
            if (BIAS) bval = bias[col];
            #pragma unroll
            for (int r = 0; r < 4; r++) {
                float v = acc[i][j][r];
                if (ELU) { if (col < 2 * NC) v = (v > 0.f) ? v + 1.f : __expf(v); }
                if (BIAS) v += bval;
                if (sizeof(OutT) == 2) Cout[(size_t)(row + r) * LDC + col] = (OutT)f2bf(v);
                else                   Cout[(size_t)(row + r) * LDC + col] = (OutT)v;
            }
        }
    }
}

// ---------- kv[b,h,d,e] = sum_n k[n,d] v[n,e];  ksum[b,h,d] = sum_n k[n,d] ----------
__global__ __launch_bounds__(256) void kv_ksum(const ushort* __restrict__ qkv,
                                               float* __restrict__ kvws,
                                               float* __restrict__ ksws) {
    __shared__ ushort klds[128 * 64];
    __shared__ ushort vlds[128 * 64];
    __shared__ float  kvred[64 * 64];
    __shared__ float  ksred[4][64];
    const int bh = blockIdx.y, b = bh / NH, h = bh % NH;
    const int t = threadIdx.x, w = t >> 6, lane = t & 63, l16 = lane & 15, quad = lane >> 4;
    const int n0 = blockIdx.x * 1024;
    const ushort* kbase = qkv + (size_t)(b * NN) * LDQKV + NC     + h * ND;
    const ushort* vbase = qkv + (size_t)(b * NN) * LDQKV + 2 * NC + h * ND;

    floatx4 acc[4][4] = {};
    float ksp = 0.f;
    const int rowT = t >> 3, ch = t & 7;   // 32 rows x 8 chunks of 16B per issue

    for (int s = 0; s < 8; s++) {
        const int nb = n0 + s * 128;
        #pragma unroll
        for (int i = 0; i < 4; i++) {
            const size_t r = (size_t)(nb + i * 32 + rowT) * LDQKV + ch * 8;
            gl_lds16(kbase + r, klds + i * 2048 + w * 512);
            gl_lds16(vbase + r, vlds + i * 2048 + w * 512);
        }
        __syncthreads();
        short8 af[4], bfr[4];
        #pragma unroll
        for (int dt = 0; dt < 4; dt++) {
            short8 v;
            #pragma unroll
            for (int j = 0; j < 8; j++)
                v[j] = (short)klds[(w * 32 + quad * 8 + j) * 64 + dt * 16 + l16];
            af[dt] = v;
        }
        #pragma unroll
        for (int et = 0; et < 4; et++) {
            short8 v;
            #pragma unroll
            for (int j = 0; j < 8; j++)
                v[j] = (short)vlds[(w * 32 + quad * 8 + j) * 64 + et * 16 + l16];
            bfr[et] = v;
        }
        #pragma unroll
        for (int dt = 0; dt < 4; dt++)
            #pragma unroll
            for (int et = 0; et < 4; et++)
                acc[dt][et] = __builtin_amdgcn_mfma_f32_16x16x32_bf16(af[dt], bfr[et], acc[dt][et], 0, 0, 0);
        #pragma unroll
        for (int n = 0; n < 32; n++) ksp += bf2f(klds[(w * 32 + n) * 64 + lane]);
        __syncthreads();
    }

    if (w == 0) {
        #pragma unroll
        for (int dt = 0; dt < 4; dt++)
            #pragma unroll
            for (int et = 0; et < 4; et++)
                #pragma unroll
                for (int r = 0; r < 4; r++)
                    kvred[(dt * 16 + quad * 4 + r) * 64 + et * 16 + l16] = acc[dt][et][r];
    }
    ksred[w][lane] = ksp;
    __syncthreads();
    if (w != 0) {
        #pragma unroll
        for (int dt = 0; dt < 4; dt++)
            #pragma unroll
            for (int et = 0; et < 4; et++)
                #pragma unroll
                for (int r = 0; r < 4; r++)
                    atomicAdd(&kvred[(dt * 16 + quad * 4 + r) * 64 + et * 16 + l16], acc[dt][et][r]);
    }
    __syncthreads();
    for (int i = t; i < 4096; i += 256) atomicAdd(&kvws[(size_t)bh * 4096 + i], kvred[i]);
    if (t < 64) atomicAdd(&ksws[bh * 64 + t], ksred[0][t] + ksred[1][t] + ksred[2][t] + ksred[3][t]);
}

// ---------- out_pre[b,n,h*64+e] = (q[n,:] @ kv) / (q[n,:]·ksum + 1e-6), bf16 ----------
__global__ __launch_bounds__(256) void attn_apply(const ushort* __restrict__ qkv,
                                                  const float* __restrict__ kvws,
                                                  const float* __restrict__ ksws,
                                                  ushort* __restrict__ outpre) {
    __shared__ ushort kvb[64 * 80];
    const int bh = blockIdx.y, b = bh / NH, h = bh % NH;
    const int t = threadIdx.x, w = t >> 6, lane = t & 63, l16 = lane & 15, quad = lane >> 4;

    for (int i = t; i < 4096; i += 256) {
        const int d = i >> 6, e = i & 63;
        kvb[d * 80 + e] = f2bf(kvws[(size_t)bh * 4096 + i]);
    }
    for (int i = t; i < 1024; i += 256) {
        const int d = i >> 4, c = i & 15;
        kvb[d * 80 + 64 + c] = (c == 0) ? f2bf(ksws[bh * 64 + d]) : (ushort)0;
    }
    __syncthreads();

    short8 bfr[5][2];
    #pragma unroll
    for (int et = 0; et < 5; et++)
        #pragma unroll
        for (int ks = 0; ks < 2; ks++) {
            short8 v;
            #pragma unroll
            for (int j = 0; j < 8; j++)
                v[j] = (short)kvb[(ks * 32 + quad * 8 + j) * 80 + et * 16 + l16];
            bfr[et][ks] = v;
        }

    const ushort* qbase = qkv + (size_t)(b * NN) * LDQKV + h * ND;
    ushort* obase = outpre + (size_t)(b * NN) * NC + h * ND;
    const int n0 = blockIdx.x * 1024;

    for (int it = 0; it < 16; it++) {
        const int nt = n0 + (it * 4 + w) * 16;
        const ushort* qp = qbase + (size_t)(nt + l16) * LDQKV + quad * 8;
        const short8 a0 = *(const short8*)qp;
        const short8 a1 = *(const short8*)(qp + 32);
        floatx4 acc[5] = {};
        #pragma unroll
        for (int et = 0; et < 5; et++) {
            acc[et] = __builtin_amdgcn_mfma_f32_16x16x32_bf16(a0, bfr[et][0], acc[et], 0, 0, 0);
            acc[et] = __builtin_amdgcn_mfma_f32_16x16x32_bf16(a1, bfr[et][1], acc[et], 0, 0, 0);
        }
        float dv[4];
        #pragma unroll
        for (int r = 0; r < 4; r++) dv[r] = __shfl(acc[4][r], lane & 48);
        #pragma unroll
        for (int et = 0; et < 4; et++)
            #pragma unroll
            for (int r = 0; r < 4; r++) {
                const float o = acc[et][r] / (dv[r] + 1e-6f);
                obase[(size_t)(nt + quad * 4 + r) * NC + et * 16 + l16] = f2bf(o);
            }
    }
}

__global__ void zero_f32(float* p, int n) {
    const int i = blockIdx.x * 256 + threadIdx.x;
    if (i < n) p[i] = 0.f;
}

extern "C" void kernel_launch(void* const* d_in, const int* in_sizes, int n_in,
                              void* d_out, int out_size, void* d_ws, size_t ws_size,
                              hipStream_t stream) {
    (void)in_sizes; (void)n_in; (void)out_size; (void)ws_size;
    const float* X     = (const float*)d_in[0];   // [4,8192,768] fp32
    const float* Wqkv  = (const float*)d_in[1];   // [2304,768]   fp32
    const float* Wproj = (const float*)d_in[2];   // [768,768]    fp32
    const float* bproj = (const float*)d_in[3];   // [768]        fp32
    float* out = (float*)d_out;                   // [4,8192,768] fp32

    char* ws = (char*)d_ws;
    size_t off = 0;
    ushort* qkv     = (ushort*)(ws + off); off += (size_t)32768 * 2304 * 2;  // 150,994,944
    ushort* outpre  = (ushort*)(ws + off); off += (size_t)32768 * 768 * 2;   //  50,331,648
    ushort* xbf     = (ushort*)(ws + off); off += (size_t)32768 * 768 * 2;   //  50,331,648
    ushort* wqkvbf  = (ushort*)(ws + off); off += (size_t)2304 * 768 * 2;    //   3,538,944
    ushort* wprojbf = (ushort*)(ws + off); off += (size_t)768 * 768 * 2;     //   1,179,648
    float*  kvws    = (float*)(ws + off);  off += (size_t)48 * 4096 * 4;     //     786,432
    float*  ksws    = (float*)(ws + off);                                     //      12,288
    // total ~245 MiB

    const int nx = 32768 * 768, nwq = 2304 * 768, nwp = 768 * 768;
    cvt_bf16<<<nx  / (256 * 8), 256, 0, stream>>>(X,     xbf,     nx);
    cvt_bf16<<<nwq / (256 * 8), 256, 0, stream>>>(Wqkv,  wqkvbf,  nwq);
    cvt_bf16<<<nwp / (256 * 8), 256, 0, stream>>>(Wproj, wprojbf, nwp);

    const int nzero = 48 * 4096 + 48 * 64;
    zero_f32<<<(nzero + 255) / 256, 256, 0, stream>>>(kvws, nzero);

    gemm_bt<LDQKV, true, false, ushort><<<dim3(18, 256), 256, 0, stream>>>(xbf, wqkvbf, nullptr, qkv, NC);
    kv_ksum<<<dim3(8, 48), 256, 0, stream>>>(qkv, kvws, ksws);
    attn_apply<<<dim3(8, 48), 256, 0, stream>>>(qkv, kvws, ksws, outpre);
    gemm_bt<NC, false, true, float><<<dim3(6, 256), 256, 0, stream>>>(outpre, wprojbf, bproj, out, NC);
}